// Round 1
// baseline (293.822 us; speedup 1.0000x reference)
//
#include <hip/hip_runtime.h>
#include <cstdint>
#include <cstddef>

// ---------- types ----------
typedef __bf16 bf16;
typedef __bf16 bf16x8 __attribute__((ext_vector_type(8)));
typedef float  floatx4 __attribute__((ext_vector_type(4)));

typedef __attribute__((address_space(1))) void gvoid_t;
typedef __attribute__((address_space(3))) void lvoid_t;

#define MFMA16(a, b, c) __builtin_amdgcn_mfma_f32_16x16x32_bf16((a), (b), (c), 0, 0, 0)

// B=2, S=2048, D=1024, H=16, DH=64; tokens NT=4096; E3=3072
#define S_TOK 2048
#define E3 3072
#define DMODEL 1024

// ---------- fp32 -> bf16 convert ----------
__global__ __launch_bounds__(256) void cvt_f32_bf16(const float* __restrict__ s,
                                                    bf16* __restrict__ d, int n) {
  int i = (blockIdx.x * 256 + threadIdx.x) * 8;
  if (i >= n) return;
  const float4* p = (const float4*)(s + i);
  float4 a = p[0], b = p[1];
  bf16x8 o;
  o[0] = (bf16)a.x; o[1] = (bf16)a.y; o[2] = (bf16)a.z; o[3] = (bf16)a.w;
  o[4] = (bf16)b.x; o[5] = (bf16)b.y; o[6] = (bf16)b.z; o[7] = (bf16)b.w;
  *(bf16x8*)(d + i) = o;
}

// ---------- async global->LDS, 16B per lane ----------
__device__ __forceinline__ void gl_lds16(const bf16* g, bf16* l) {
  __builtin_amdgcn_global_load_lds((gvoid_t*)g, (lvoid_t*)l, 16, 0, 0);
}

// ---------- GEMM: C[m][n] = sum_k A[m][k] * Bt[n][k]  (m97 structure) ----------
// 128x128 tile, BK=32, 256 threads / 4 waves in 2x2, each wave 64x64 (4x4 MFMA tiles)
template <bool OUT_BF16>
__global__ __launch_bounds__(256) void gemm_bt(const bf16* __restrict__ A,
                                               const bf16* __restrict__ Bt,
                                               void* __restrict__ Cv,
                                               int M, int N, int K) {
  __shared__ bf16 sA[128 * 32];
  __shared__ bf16 sB[128 * 32];
  const int tid = threadIdx.x;
  const int wv = tid >> 6, lane = tid & 63;
  const int wr = wv >> 1, wc = wv & 1;
  const int lrow = lane & 15, lgrp = lane >> 4;
  const int R0 = blockIdx.y * 128, C0 = blockIdx.x * 128;

  floatx4 acc[4][4] = {};

  const bf16* gA = A + (size_t)(R0 + wv * 32 + (lane >> 2)) * K + (lane & 3) * 8;
  const bf16* gB = Bt + (size_t)(C0 + wv * 32 + (lane >> 2)) * K + (lane & 3) * 8;
  bf16* lA = sA + wv * 1024;  // wave-uniform LDS base; HW scatters lane i at +16B*i
  bf16* lB = sB + wv * 1024;
  const size_t rowstep = (size_t)16 * K;

  for (int k0 = 0; k0 < K; k0 += 32) {
    gl_lds16(gA + k0, lA);
    gl_lds16(gA + k0 + rowstep, lA + 512);
    gl_lds16(gB + k0, lB);
    gl_lds16(gB + k0 + rowstep, lB + 512);
    __syncthreads();  // drains vmcnt -> staged data visible
    bf16x8 af[4], bfr[4];
#pragma unroll
    for (int i = 0; i < 4; i++)
      af[i] = *(const bf16x8*)&sA[(wr * 64 + i * 16 + lrow) * 32 + lgrp * 8];
#pragma unroll
    for (int j = 0; j < 4; j++)
      bfr[j] = *(const bf16x8*)&sB[(wc * 64 + j * 16 + lrow) * 32 + lgrp * 8];
#pragma unroll
    for (int i = 0; i < 4; i++)
#pragma unroll
      for (int j = 0; j < 4; j++)
        acc[i][j] = MFMA16(af[i], bfr[j], acc[i][j]);
    __syncthreads();  // all waves done reading before restage
  }

  const int rbase = R0 + wr * 64 + lgrp * 4;
  const int cbase = C0 + wc * 64 + lrow;
  if (OUT_BF16) {
    bf16* C = (bf16*)Cv;
#pragma unroll
    for (int i = 0; i < 4; i++)
#pragma unroll
      for (int j = 0; j < 4; j++)
#pragma unroll
        for (int r = 0; r < 4; r++)
          C[(size_t)(rbase + i * 16 + r) * N + cbase + j * 16] = (bf16)acc[i][j][r];
  } else {
    float* C = (float*)Cv;
#pragma unroll
    for (int i = 0; i < 4; i++)
#pragma unroll
      for (int j = 0; j < 4; j++)
#pragma unroll
        for (int r = 0; r < 4; r++)
          C[(size_t)(rbase + i * 16 + r) * N + cbase + j * 16] = acc[i][j][r];
  }
}

// ---------- V transpose with sigma permutation baked in ----------
// Vt[(b*16+h)*64 + d][s'] = V[b][s][h][d],  s' = (s&~31) | ((s&15)<<1) | ((s>>4)&1)
__global__ __launch_bounds__(256) void transpose_v(const bf16* __restrict__ qkv,
                                                   bf16* __restrict__ Vt) {
  __shared__ bf16 sT[64 * 72];  // [d][s_local], stride 72 kills write conflicts
  const int tid = threadIdx.x;
  const int b = blockIdx.z, h = blockIdx.y, s0 = blockIdx.x * 64;
  const bf16* vsrc = qkv + (size_t)(b * S_TOK + s0) * E3 + h * 192 + 128;
#pragma unroll
  for (int j = 0; j < 8; j++) {
    int idx = tid + 256 * j;
    int sl = idx & 63, dp = idx >> 6;  // dp wave-uniform -> conflict-free writes
    unsigned u = *(const unsigned*)(vsrc + (size_t)sl * E3 + 2 * dp);
    sT[(2 * dp) * 72 + sl] = __builtin_bit_cast(bf16, (unsigned short)(u & 0xffffu));
    sT[(2 * dp + 1) * 72 + sl] = __builtin_bit_cast(bf16, (unsigned short)(u >> 16));
  }
  __syncthreads();
  bf16* vdst = Vt + ((size_t)(b * 16 + h) * 64) * S_TOK + s0;
#pragma unroll
  for (int j = 0; j < 2; j++) {
    int idx = tid + 256 * j;
    int d = idx >> 3, sc8 = (idx & 7) * 8;
    bf16x8 o;
#pragma unroll
    for (int m2 = 0; m2 < 8; m2++) {
      int sp = sc8 + m2;  // permuted position; invert sigma to find source s
      int ss = (sp & ~31) | ((sp >> 1) & 15) | ((sp & 1) << 4);
      o[m2] = sT[d * 72 + ss];
    }
    *(bf16x8*)(vdst + (size_t)d * S_TOK + sc8) = o;
  }
}

// ---------- fused attention: no online softmax (scores bounded), l via MFMA-ones ----------
// block = 128 thr (2 waves); each wave owns 64 q-rows; loop 64 key-tiles of 32.
// K-frags & Vt-frags straight from global (L2); only LDS use: P layout round-trip.
__global__ __launch_bounds__(128) void attn(const bf16* __restrict__ qkv,
                                            const bf16* __restrict__ Vt,
                                            bf16* __restrict__ vals) {
  __shared__ bf16 sP[2][4][16 * 40];  // [wave][rowtile][16 rows x stride 40]
  const int tid = threadIdx.x;
  const int wv = tid >> 6, lane = tid & 63;
  const int lrow = lane & 15, lgrp = lane >> 4;
  const int b = blockIdx.z, h = blockIdx.y;
  const int qbase = blockIdx.x * 128 + wv * 64;

  const bf16* qp = qkv + (size_t)(b * S_TOK + qbase) * E3 + h * 192;
  const bf16* kp = qkv + (size_t)(b * S_TOK) * E3 + h * 192 + 64;
  const bf16* vp = Vt + (size_t)((b * 16 + h) * 64) * S_TOK;

  // Q A-fragments hoisted to registers: A[m=lane&15][k=lgrp*8+j]
  bf16x8 qa[4][2];
#pragma unroll
  for (int rt = 0; rt < 4; rt++)
#pragma unroll
    for (int dh = 0; dh < 2; dh++)
      qa[rt][dh] = *(const bf16x8*)(qp + (size_t)(rt * 16 + lrow) * E3 + dh * 32 + lgrp * 8);

  floatx4 O[4][4] = {};
  floatx4 lacc[4] = {};
  bf16x8 ones;
  const bf16 one1 = (bf16)1.0f;
#pragma unroll
  for (int j = 0; j < 8; j++) ones[j] = one1;

  const float C8 = 0.18033688011f;  // 0.125 * log2(e)

  for (int kt = 0; kt < S_TOK / 32; kt++) {
    bf16x8 kf[2][2], vf[4];
#pragma unroll
    for (int t = 0; t < 2; t++)
#pragma unroll
      for (int dh = 0; dh < 2; dh++)
        kf[t][dh] = *(const bf16x8*)(kp + (size_t)(kt * 32 + t * 16 + lrow) * E3 + dh * 32 + lgrp * 8);
#pragma unroll
    for (int dt = 0; dt < 4; dt++)
      vf[dt] = *(const bf16x8*)(vp + (size_t)(dt * 16 + lrow) * S_TOK + kt * 32 + lgrp * 8);

    // QK^T, exp, pack P into LDS in A-layout-friendly order (sigma: cols 2c,2c+1)
#pragma unroll
    for (int rt = 0; rt < 4; rt++) {
      floatx4 sc0 = {0.f, 0.f, 0.f, 0.f}, sc1 = {0.f, 0.f, 0.f, 0.f};
      sc0 = MFMA16(qa[rt][0], kf[0][0], sc0);
      sc0 = MFMA16(qa[rt][1], kf[0][1], sc0);
      sc1 = MFMA16(qa[rt][0], kf[1][0], sc1);
      sc1 = MFMA16(qa[rt][1], kf[1][1], sc1);
#pragma unroll
      for (int r = 0; r < 4; r++) {
        float p0 = exp2f(sc0[r] * C8);
        float p1 = exp2f(sc1[r] * C8);
        unsigned u = (unsigned)__builtin_bit_cast(unsigned short, (bf16)p0) |
                     ((unsigned)__builtin_bit_cast(unsigned short, (bf16)p1) << 16);
        *(unsigned*)&sP[wv][rt][(lgrp * 4 + r) * 40 + lrow * 2] = u;
      }
    }
    // P back as A-frags; PV + row-sum via ones-column MFMA
#pragma unroll
    for (int rt = 0; rt < 4; rt++) {
      bf16x8 pf = *(const bf16x8*)&sP[wv][rt][lrow * 40 + lgrp * 8];
#pragma unroll
      for (int dt = 0; dt < 4; dt++) O[rt][dt] = MFMA16(pf, vf[dt], O[rt][dt]);
      lacc[rt] = MFMA16(pf, ones, lacc[rt]);
    }
  }

  // epilogue: normalize by row sums (same C-layout rows as O) and store
  bf16* vout = vals + (size_t)(b * S_TOK + qbase) * DMODEL + h * 64;
#pragma unroll
  for (int rt = 0; rt < 4; rt++) {
#pragma unroll
    for (int r = 0; r < 4; r++) {
      float rinv = __builtin_amdgcn_rcpf(lacc[rt][r]);
#pragma unroll
      for (int dt = 0; dt < 4; dt++)
        vout[(size_t)(rt * 16 + lgrp * 4 + r) * DMODEL + dt * 16 + lrow] =
            (bf16)(O[rt][dt][r] * rinv);
    }
  }
}

// ---------- host ----------
extern "C" void kernel_launch(void* const* d_in, const int* in_sizes, int n_in,
                              void* d_out, int out_size, void* d_ws, size_t ws_size,
                              hipStream_t stream) {
  const float* X = (const float*)d_in[0];     // (2,2048,1024)
  const float* Wqkv = (const float*)d_in[1];  // (3072,1024)
  const float* Wout = (const float*)d_in[2];  // (1024,1024)
  float* out = (float*)d_out;                 // (2,2048,1024)

  char* ws = (char*)d_ws;
  bf16* Xb = (bf16*)(ws);                          //  8 MB
  bf16* Wqb = (bf16*)(ws + ((size_t)8 << 20));     //  6 MB
  bf16* Wob = (bf16*)(ws + ((size_t)14 << 20));    //  2 MB
  bf16* qkvb = (bf16*)(ws + ((size_t)16 << 20));   // 24 MB (4096 x 3072)
  bf16* Vt = (bf16*)(ws + ((size_t)40 << 20));     //  8 MB (2*16*64 x 2048)
  bf16* vals = (bf16*)(ws + ((size_t)48 << 20));   //  8 MB (4096 x 1024)

  cvt_f32_bf16<<<4194304 / 2048, 256, 0, stream>>>(X, Xb, 4194304);
  cvt_f32_bf16<<<3145728 / 2048, 256, 0, stream>>>(Wqkv, Wqb, 3145728);
  cvt_f32_bf16<<<1048576 / 2048, 256, 0, stream>>>(Wout, Wob, 1048576);

  // qkv = X @ Wqkv^T : (4096,1024)x(3072,1024)^T -> (4096,3072) bf16
  gemm_bt<true><<<dim3(24, 32), 256, 0, stream>>>(Xb, Wqb, qkvb, 4096, 3072, 1024);

  transpose_v<<<dim3(32, 16, 2), 256, 0, stream>>>(qkvb, Vt);

  attn<<<dim3(16, 16, 2), 128, 0, stream>>>(qkvb, Vt, vals);

  // out = vals @ Wout^T : (4096,1024)x(1024,1024)^T -> (4096,1024) fp32
  gemm_bt<false><<<dim3(8, 32), 256, 0, stream>>>(vals, Wob, out, 4096, 1024, 1024);
}